// Round 3
// baseline (40674.710 us; speedup 1.0000x reference)
//
#include <hip/hip_runtime.h>
#include <hip/hip_bf16.h>
#include <cstdint>
#include <cstddef>

#define RNG_PART 1

typedef __bf16 bf16x8 __attribute__((ext_vector_type(8)));
typedef float f32x4 __attribute__((ext_vector_type(4)));
typedef unsigned short ushort_t;

// ---------------- sizes: B=256, T=256, ZS=128, ZT=64, H=512, 3H=1536
// ---------------- workspace layout (float offsets)
static constexpr size_t ACC0 = 0;                 // [256][1536] f32 static xp0 (+b_ih0)
static constexpr size_t SHH  = 393216;            // [256][512] static_h
static constexpr size_t HID  = 524288;            // [256][512] fc1 hidden
static constexpr size_t H0F  = 655360;            // [2][256][512] f32 ping-pong h0
static constexpr size_t H1F  = 917504;            // [2][256][512] f32 ping-pong h1
static constexpr size_t H0S  = 1179648;           // [2][3][256][512] bf16 splits of h0 (786432 ush)
static constexpr size_t H1S  = 1572864;           // same for h1
static constexpr size_t WTH  = 1966080;           // [512][64] f32 gathered head weights
static constexpr size_t W2B  = 1998848;           // bf16 w2 (3rd split) planes: B|A|H
static constexpr size_t PREG = 3244032;           // partials region (overlaid: FC1T/FC2T/WIS, then WS01 staging)
static constexpr size_t BARO = 8945664;           // barrier (2 u32)
// partials (float offsets)
static constexpr size_t PB1 = PREG;               // [24][256][512] f32 = 3145728
static constexpr size_t PA0 = PREG + 3145728;     // [19][256][512] f32 = 2490368
static constexpr size_t PCC = PREG + 5636096;     // [4][256][64] f32 = 65536
// pre-loop overlays in PREG
static constexpr size_t FC1T = PREG;              // [128][512]
static constexpr size_t FC2T = PREG + 65536;      // [512][512]
static constexpr size_t WIS  = PREG + 327680;     // [512][1536]
// ushort offsets (relative to their base pointers)
static constexpr size_t WS01A_OFS = 3145728;      // ushorts into ws01 base
static constexpr size_t WS01H_OFS = 4915200;
static constexpr size_t W2BA_OFS  = 1572864;      // ushorts into w2b base
static constexpr size_t W2BH_OFS  = 2457600;

static constexpr int NBLK = 228;
static constexpr int NTHR = 116736;  // 228*512

// ---------------- output layout (float offsets)
static constexpr size_t O_SCONT = 0;
static constexpr size_t O_SCAT  = 4096;
static constexpr size_t O_TCONT = 6656;
static constexpr size_t O_IRR0  = 2103808;
static constexpr size_t O_IRR1  = 2234880;
static constexpr size_t O_CAT0  = 2365952;
static constexpr size_t O_CAT1  = 2890240;
static constexpr size_t O_VMASK = 3938816;
static constexpr size_t O_VTIME = 4004352;

// ---------------- threefry2x32-20
__host__ __device__ inline void tf2x32(unsigned k0, unsigned k1, unsigned x0, unsigned x1,
                                       unsigned* o0, unsigned* o1) {
  unsigned ks2 = k0 ^ k1 ^ 0x1BD11BDAu;
#define TFR(r) { x0 += x1; x1 = (x1 << (r)) | (x1 >> (32 - (r))); x1 ^= x0; }
  x0 += k0; x1 += k1;
  TFR(13) TFR(15) TFR(26) TFR(6)
  x0 += k1; x1 += ks2 + 1u;
  TFR(17) TFR(29) TFR(16) TFR(24)
  x0 += ks2; x1 += k0 + 2u;
  TFR(13) TFR(15) TFR(26) TFR(6)
  x0 += k0; x1 += k1 + 3u;
  TFR(17) TFR(29) TFR(16) TFR(24)
  x0 += k1; x1 += ks2 + 4u;
  TFR(13) TFR(15) TFR(26) TFR(6)
  x0 += ks2; x1 += k0 + 5u;
#undef TFR
  *o0 = x0; *o1 = x1;
}

__device__ inline float rng_u01(unsigned k0, unsigned k1, unsigned idx) {
  unsigned o0, o1;
  tf2x32(k0, k1, 0u, idx, &o0, &o1);
  unsigned bits = o0 ^ o1;
  return __uint_as_float((bits >> 9) | 0x3f800000u) - 1.0f;
}

__device__ inline float sigmoidf_(float x) { return 1.0f / (1.0f + expf(-x)); }

// ---------------- tiled transpose
__global__ __launch_bounds__(256) void transpose_k(const float* __restrict__ src, float* __restrict__ dst,
                                                   int J, int K, int srcStride, int dstStride) {
  __shared__ float tile[32][33];
  int kb = blockIdx.x * 32, jb = blockIdx.y * 32;
  int tx = threadIdx.x & 31, ty = threadIdx.x >> 5;
  #pragma unroll
  for (int r = 0; r < 4; ++r) {
    int j = jb + ty + r * 8, k = kb + tx;
    if (j < J && k < K) tile[ty + r * 8][tx] = src[(size_t)j * srcStride + k];
  }
  __syncthreads();
  #pragma unroll
  for (int r = 0; r < 4; ++r) {
    int k = kb + ty + r * 8, j = jb + tx;
    if (k < K && j < J) dst[(size_t)k * dstStride + j] = tile[tx][ty + r * 8];
  }
}

// ---------------- gather head weights into wtH[512][64] (cols 60..63 zero)
__global__ void hgather_k(const float* __restrict__ time_w, const float* __restrict__ visit_w,
                          const float* __restrict__ tcont_w, const float* __restrict__ irr0_w,
                          const float* __restrict__ irr1_w, const float* __restrict__ cat0_w,
                          const float* __restrict__ cat1_w, float* __restrict__ wtH) {
  int c = blockIdx.x;
  if (c >= 60) {
    for (int k = threadIdx.x; k < 512; k += blockDim.x) wtH[(size_t)k * 64 + c] = 0.0f;
    return;
  }
  const float* src;
  if (c == 0) src = time_w;
  else if (c == 1) src = visit_w;
  else if (c < 34) src = tcont_w + (size_t)(c - 2) * 512;
  else if (c == 34) src = irr0_w;
  else if (c == 35) src = irr1_w;
  else if (c < 44) src = cat0_w + (size_t)(c - 36) * 512;
  else src = cat1_w + (size_t)(c - 44) * 512;
  for (int k = threadIdx.x; k < 512; k += blockDim.x) wtH[(size_t)k * 64 + c] = src[k];
}

// ---------------- fp32 GEMM (pre-loop static path)
__global__ __launch_bounds__(128) void gemm_k(const float* __restrict__ in, const float* __restrict__ wT,
                                              const float* __restrict__ bias, float* __restrict__ out,
                                              int M, int K, int J, int relu) {
  __shared__ float ibuf[64][34];
  __shared__ float wbuf[64][36];
  int jt = blockIdx.x % (J >> 5), mt = blockIdx.x / (J >> 5);
  int m0 = mt * 32, j0 = jt * 32;
  int tid = threadIdx.x;
  int mq = tid & 15, jq = tid >> 4;
  float acc[2][4] = {{0.f, 0.f, 0.f, 0.f}, {0.f, 0.f, 0.f, 0.f}};
  for (int kc = 0; kc < K; kc += 64) {
    __syncthreads();
    #pragma unroll
    for (int i = 0; i < 16; ++i) {
      int lin = i * 128 + tid;
      int k = lin & 63, m = lin >> 6;
      ibuf[k][m] = in[(size_t)(m0 + m) * K + kc + k];
    }
    #pragma unroll
    for (int i = 0; i < 16; ++i) {
      int lin = i * 128 + tid;
      int c = lin & 31, k = lin >> 5;
      wbuf[k][c] = wT[(size_t)(kc + k) * J + j0 + c];
    }
    __syncthreads();
    #pragma unroll 8
    for (int k = 0; k < 64; ++k) {
      float i0 = ibuf[k][2 * mq], i1 = ibuf[k][2 * mq + 1];
      const float4 w = *(const float4*)&wbuf[k][4 * jq];
      acc[0][0] += i0 * w.x; acc[0][1] += i0 * w.y; acc[0][2] += i0 * w.z; acc[0][3] += i0 * w.w;
      acc[1][0] += i1 * w.x; acc[1][1] += i1 * w.y; acc[1][2] += i1 * w.z; acc[1][3] += i1 * w.w;
    }
  }
  #pragma unroll
  for (int mi = 0; mi < 2; ++mi)
    #pragma unroll
    for (int ji = 0; ji < 4; ++ji) {
      int j = j0 + 4 * jq + ji;
      float v = acc[mi][ji] + bias[j];
      if (relu) v = fmaxf(v, 0.0f);
      out[(size_t)(m0 + 2 * mq + mi) * J + j] = v;
    }
}

// ---------------- weight arrangement: 3-way bf16 split; s0/s1 -> ws01 (staging), s2 -> w2b
__device__ inline void split3_store(float v, ushort_t* p0, ushort_t* p1, ushort_t* p2) {
  __bf16 t0 = (__bf16)v; float r1 = v - (float)t0;
  __bf16 t1 = (__bf16)r1; float r2 = r1 - (float)t1;
  __bf16 t2 = (__bf16)r2;
  *p0 = __builtin_bit_cast(ushort_t, t0);
  *p1 = __builtin_bit_cast(ushort_t, t1);
  *p2 = __builtin_bit_cast(ushort_t, t2);
}

__global__ __launch_bounds__(256) void arrangeB1_k(const float* __restrict__ w_ih1,
                                                   const float* __restrict__ w_hh1,
                                                   ushort_t* __restrict__ ws01, ushort_t* __restrict__ w2b) {
  int id = blockIdx.x * 256 + threadIdx.x;          // (kc,ht,g,l): 32*32*3*64
  if (id >= 32 * 32 * 3 * 64) return;
  int l = id & 63; int rest = id >> 6;
  int g = rest % 3; rest /= 3;
  int ht = rest & 31; int kc = rest >> 5;
  int n = g * 512 + ht * 16 + (l & 15);
  int kbase = kc * 32 + (l >> 4) * 8;
  size_t f = (size_t)((kc * 32 + ht) * 3 + g);
  #pragma unroll
  for (int j = 0; j < 8; ++j) {
    int k = kbase + j;
    float v = (k < 512) ? w_ih1[(size_t)n * 512 + k] : w_hh1[(size_t)n * 512 + (k - 512)];
    split3_store(v, ws01 + f * 1024 + l * 8 + j, ws01 + f * 1024 + 512 + l * 8 + j,
                 w2b + f * 512 + l * 8 + j);
  }
}

__global__ __launch_bounds__(256) void arrangeA0_k(const float* __restrict__ w_hh0,
                                                   const float* __restrict__ w_ih0,
                                                   ushort_t* __restrict__ ws01, ushort_t* __restrict__ w2b) {
  int id = blockIdx.x * 256 + threadIdx.x;          // (kc,ht,g,l): 18*32*3*64
  if (id >= 18 * 32 * 3 * 64) return;
  int l = id & 63; int rest = id >> 6;
  int g = rest % 3; rest /= 3;
  int ht = rest & 31; int kc = rest >> 5;
  int n = g * 512 + ht * 16 + (l & 15);
  int kbase = kc * 32 + (l >> 4) * 8;
  size_t f = (size_t)((kc * 32 + ht) * 3 + g);
  #pragma unroll
  for (int j = 0; j < 8; ++j) {
    int k = kbase + j;
    float v = (k < 512) ? w_hh0[(size_t)n * 512 + k] : w_ih0[(size_t)n * 576 + (k - 512)];
    split3_store(v, ws01 + f * 1024 + l * 8 + j, ws01 + f * 1024 + 512 + l * 8 + j,
                 w2b + f * 512 + l * 8 + j);
  }
}

__global__ __launch_bounds__(256) void arrangeH_k(const float* __restrict__ wtH,
                                                  ushort_t* __restrict__ ws01, ushort_t* __restrict__ w2b) {
  int id = blockIdx.x * 256 + threadIdx.x;          // (kc,ct,l): 16*4*64
  if (id >= 16 * 4 * 64) return;
  int l = id & 63; int rest = id >> 6;
  int ct = rest & 3; int kc = rest >> 2;
  int c = ct * 16 + (l & 15);
  int kbase = kc * 32 + (l >> 4) * 8;
  size_t f = (size_t)(kc * 4 + ct);
  #pragma unroll
  for (int j = 0; j < 8; ++j) {
    float v = wtH[(size_t)(kbase + j) * 64 + c];
    split3_store(v, ws01 + f * 1024 + l * 8 + j, ws01 + f * 1024 + 512 + l * 8 + j,
                 w2b + f * 512 + l * 8 + j);
  }
}

// ---------------- MFMA helpers
__device__ inline bf16x8 ldb8(const ushort_t* p) { return *reinterpret_cast<const bf16x8*>(p); }
#define MFMA_(A, W, C) __builtin_amdgcn_mfma_f32_16x16x32_bf16((A), (W), (C), 0, 0, 0)

struct HeadPtrs {
  const float *time_b, *visit_b, *tcont_b, *irr0_b, *irr1_b, *cat0_b, *cat1_b;
};
struct Keys { unsigned kv0, kv1, ki00, ki01, ki10, ki11, kc00, kc01, kc10, kc11; };

__device__ inline float head_bias(const HeadPtrs& hp, int c) {
  if (c == 0) return hp.time_b[0];
  if (c == 1) return hp.visit_b[0];
  if (c < 34) return hp.tcont_b[c - 2];
  if (c == 34) return hp.irr0_b[0];
  if (c == 35) return hp.irr1_b[0];
  if (c < 44) return hp.cat0_b[c - 36];
  return hp.cat1_b[c - 44];
}

// ---------------- grid barrier (all 228 blocks co-resident: 228<=256 CUs, 48KB LDS, VGPR<=256)
__device__ inline void gridbar(unsigned* bar, unsigned* bgen) {
  __syncthreads();
  if (threadIdx.x == 0) {
    __threadfence();
    unsigned g0 = *bgen;
    unsigned t = __hip_atomic_fetch_add(&bar[0], 1u, __ATOMIC_ACQ_REL, __HIP_MEMORY_SCOPE_AGENT);
    if (t == (unsigned)(NBLK - 1)) {
      __hip_atomic_store(&bar[0], 0u, __ATOMIC_RELAXED, __HIP_MEMORY_SCOPE_AGENT);
      __hip_atomic_fetch_add(&bar[1], 1u, __ATOMIC_ACQ_REL, __HIP_MEMORY_SCOPE_AGENT);
    } else {
      while (__hip_atomic_load(&bar[1], __ATOMIC_ACQUIRE, __HIP_MEMORY_SCOPE_AGENT) == g0) {
        __builtin_amdgcn_s_sleep(4);
      }
    }
    __threadfence();
    *bgen = g0 + 1u;
  }
  __syncthreads();
}

// ---------------- 6-product accumulate
#define MM6(ACCV, A0, A1, A2, W0, W1, W2) \
  { f32x4 c_ = (ACCV); \
    c_ = MFMA_((A0), (W0), c_); c_ = MFMA_((A0), (W1), c_); \
    c_ = MFMA_((A1), (W0), c_); c_ = MFMA_((A1), (W1), c_); \
    c_ = MFMA_((A0), (W2), c_); c_ = MFMA_((A2), (W0), c_); \
    (ACCV) = c_; }

// ---------------- the persistent kernel
__global__ __launch_bounds__(512, 2) void persistent_k(
    const float* __restrict__ z_temporal,
    const float* __restrict__ b_hh0, const float* __restrict__ b_ih1, const float* __restrict__ b_hh1,
    HeadPtrs hp, Keys ky, float* __restrict__ ws, float* __restrict__ out)
{
  __shared__ ushort_t ldsw[24576];   // 48 KB
  const int blk = blockIdx.x, tid = threadIdx.x;
  const int wv = tid >> 6, l = tid & 63, lm = l & 15, lq = l >> 4;

  unsigned* bar = (unsigned*)(ws + BARO);
  unsigned bgen = 0;

  ushort_t* h0sB = (ushort_t*)(ws + H0S);
  ushort_t* h1sB = (ushort_t*)(ws + H1S);
  const ushort_t* ws01 = (const ushort_t*)(ws + PREG);
  const ushort_t* w2bB = (const ushort_t*)(ws + W2B);
  const ushort_t* w2bA = w2bB + W2BA_OFS;
  const ushort_t* w2bH = w2bB + W2BH_OFS;

  // ---- stage w0/w1 weight planes into LDS (once)
  if (blk < 128) {                 // B job: nn=blk>>3, kq=blk&7
    const int nn = blk >> 3, kq = blk & 7;
    for (int fl = wv; fl < 48; fl += 8) {
      int sl = fl & 1, q = fl >> 1;
      int g = q % 3, p = q / 3;
      int nt = p & 1, kcl = p >> 1;
      size_t f = (size_t)((kq * 4 + kcl) * 32 + (nn * 2 + nt)) * 3 + g;
      *(bf16x8*)&ldsw[(size_t)fl * 512 + l * 8] = ldb8(ws01 + f * 1024 + sl * 512 + l * 8);
    }
  } else if (blk < 224) {          // A job: nn=ba/6, kq=ba%6
    const int ba = blk - 128, nn = ba / 6, kq = ba % 6;
    for (int fl = wv; fl < 36; fl += 8) {
      int sl = fl & 1, q = fl >> 1;
      int g = q % 3, p = q / 3;
      int nt = p & 1, kcl = p >> 1;
      size_t f = (size_t)((3 * kq + kcl) * 32 + (nn * 2 + nt)) * 3 + g;
      *(bf16x8*)&ldsw[(size_t)fl * 512 + l * 8] = ldb8(ws01 + WS01A_OFS + f * 1024 + sl * 512 + l * 8);
    }
  } else {                         // C job: kq = blk-224
    const int kq = blk - 224;
    for (int fl = wv; fl < 32; fl += 8) {
      int sl = fl & 1, q = fl >> 1;
      int ct = q & 3, kcl = q >> 2;
      size_t f = (size_t)((4 * kq + kcl) * 4 + ct);
      *(bf16x8*)&ldsw[(size_t)fl * 512 + l * 8] = ldb8(ws01 + WS01H_OFS + f * 1024 + sl * 512 + l * 8);
    }
  }
  gridbar(bar, &bgen);

  // ---- streaming scan state (heads threads only; lane-role registers)
  float st_cum = 0.f, st_v = 0.f, st_i0 = 0.f, st_i1 = 0.f;

  for (int s = 0; s <= 257; ++s) {
    // ============ phase 1: GEMM partials ============
    if (blk < 128) {
      // B: h1_{s-1} partials; K slice kq of [h0(512) ++ h1(512)]
      if (s >= 1 && s <= 256) {
        const int nn = blk >> 3, kq = blk & 7;
        const ushort_t* act;
        int kbase;
        if (kq < 4) { act = h0sB + (size_t)((s - 1) & 1) * 393216; kbase = kq * 128; }
        else        { act = h1sB + (size_t)(s & 1) * 393216;       kbase = kq * 128 - 512; }
        f32x4 acc[2][2][3] = {};
        const int mtb = wv * 2;
        for (int kcl = 0; kcl < 4; ++kcl) {
          const int k0 = kbase + kcl * 32 + lq * 8;
          bf16x8 a[2][3];
          #pragma unroll
          for (int mt = 0; mt < 2; ++mt) {
            const size_t o = (size_t)((mtb + mt) * 16 + lm) * 512 + k0;
            a[mt][0] = ldb8(act + o);
            a[mt][1] = ldb8(act + 131072 + o);
            a[mt][2] = ldb8(act + 262144 + o);
          }
          #pragma unroll
          for (int nt = 0; nt < 2; ++nt) {
            #pragma unroll
            for (int g = 0; g < 3; ++g) {
              const int fb = ((kcl * 2 + nt) * 3 + g) * 2;
              bf16x8 w0 = *(const bf16x8*)&ldsw[(size_t)fb * 512 + l * 8];
              bf16x8 w1 = *(const bf16x8*)&ldsw[(size_t)(fb + 1) * 512 + l * 8];
              size_t f = (size_t)((kq * 4 + kcl) * 32 + (nn * 2 + nt)) * 3 + g;
              bf16x8 w2 = ldb8(w2bB + f * 512 + l * 8);
              MM6(acc[0][nt][g], a[0][0], a[0][1], a[0][2], w0, w1, w2);
              MM6(acc[1][nt][g], a[1][0], a[1][1], a[1][2], w0, w1, w2);
            }
          }
        }
        float* PB = ws + PB1;
        #pragma unroll
        for (int mt = 0; mt < 2; ++mt)
          #pragma unroll
          for (int nt = 0; nt < 2; ++nt)
            #pragma unroll
            for (int g = 0; g < 3; ++g)
              #pragma unroll
              for (int r = 0; r < 4; ++r) {
                int brow = (mtb + mt) * 16 + lq * 4 + r;
                int h = nn * 32 + nt * 16 + lm;
                PB[(size_t)(kq * 3 + g) * 131072 + (size_t)brow * 512 + h] = acc[mt][nt][g][r];
              }
      }
    } else if (blk < 224) {
      // A: h0_s partials; K slice kq of [h0(512) ++ z(64)] (kcg 16,17 are z)
      if (s <= 255) {
        const int ba = blk - 128, nn = ba / 6, kq = ba % 6;
        const ushort_t* act = h0sB + (size_t)((s + 1) & 1) * 393216;
        f32x4 acc[2][2][3] = {};
        f32x4 accz[2][2] = {};
        const int mtb = wv * 2;
        for (int kcl = 0; kcl < 3; ++kcl) {
          const int kcg = 3 * kq + kcl;
          const bool isz = (kcg >= 16);
          bf16x8 a[2][3];
          if (!isz) {
            const int k0 = kcg * 32 + lq * 8;
            #pragma unroll
            for (int mt = 0; mt < 2; ++mt) {
              const size_t o = (size_t)((mtb + mt) * 16 + lm) * 512 + k0;
              a[mt][0] = ldb8(act + o);
              a[mt][1] = ldb8(act + 131072 + o);
              a[mt][2] = ldb8(act + 262144 + o);
            }
          } else {
            #pragma unroll
            for (int mt = 0; mt < 2; ++mt) {
              const int row = (mtb + mt) * 16 + lm;
              const float* zp = z_temporal + ((size_t)row * 256 + s) * 64 + (kcg - 16) * 32 + lq * 8;
              float4 q0 = *(const float4*)zp;
              float4 q1 = *(const float4*)(zp + 4);
              float vals[8] = {q0.x, q0.y, q0.z, q0.w, q1.x, q1.y, q1.z, q1.w};
              bf16x8 b0v, b1v, b2v;
              #pragma unroll
              for (int j = 0; j < 8; ++j) {
                float v = vals[j];
                __bf16 t0 = (__bf16)v; float r1 = v - (float)t0;
                __bf16 t1 = (__bf16)r1; float r2 = r1 - (float)t1;
                b0v[j] = t0; b1v[j] = t1; b2v[j] = (__bf16)r2;
              }
              a[mt][0] = b0v; a[mt][1] = b1v; a[mt][2] = b2v;
            }
          }
          #pragma unroll
          for (int nt = 0; nt < 2; ++nt) {
            #pragma unroll
            for (int g = 0; g < 3; ++g) {
              const int fb = ((kcl * 2 + nt) * 3 + g) * 2;
              bf16x8 w0 = *(const bf16x8*)&ldsw[(size_t)fb * 512 + l * 8];
              bf16x8 w1 = *(const bf16x8*)&ldsw[(size_t)(fb + 1) * 512 + l * 8];
              size_t f = (size_t)(kcg * 32 + (nn * 2 + nt)) * 3 + g;
              bf16x8 w2 = ldb8(w2bA + f * 512 + l * 8);
              if (g == 2 && isz) {
                MM6(accz[0][nt], a[0][0], a[0][1], a[0][2], w0, w1, w2);
                MM6(accz[1][nt], a[1][0], a[1][1], a[1][2], w0, w1, w2);
              } else {
                MM6(acc[0][nt][g], a[0][0], a[0][1], a[0][2], w0, w1, w2);
                MM6(acc[1][nt][g], a[1][0], a[1][1], a[1][2], w0, w1, w2);
              }
            }
          }
        }
        float* PA = ws + PA0;
        #pragma unroll
        for (int mt = 0; mt < 2; ++mt)
          #pragma unroll
          for (int nt = 0; nt < 2; ++nt) {
            int h = nn * 32 + nt * 16 + lm;
            #pragma unroll
            for (int g = 0; g < 3; ++g)
              #pragma unroll
              for (int r = 0; r < 4; ++r) {
                int brow = (mtb + mt) * 16 + lq * 4 + r;
                PA[(size_t)(kq * 3 + g) * 131072 + (size_t)brow * 512 + h] = acc[mt][nt][g][r];
              }
            if (kq == 5) {
              #pragma unroll
              for (int r = 0; r < 4; ++r) {
                int brow = (mtb + mt) * 16 + lq * 4 + r;
                PA[(size_t)18 * 131072 + (size_t)brow * 512 + h] = accz[mt][nt][r];
              }
            }
          }
      }
    } else {
      // C: head logits partials for t=s-2 from h1_{s-2}
      if (s >= 2) {
        const int kq = blk - 224;
        const ushort_t* act = h1sB + (size_t)(s & 1) * 393216;
        f32x4 acc[2][4] = {};
        const int mtb = wv * 2;
        for (int kcl = 0; kcl < 4; ++kcl) {
          const int k0 = kq * 128 + kcl * 32 + lq * 8;
          bf16x8 a[2][3];
          #pragma unroll
          for (int mt = 0; mt < 2; ++mt) {
            const size_t o = (size_t)((mtb + mt) * 16 + lm) * 512 + k0;
            a[mt][0] = ldb8(act + o);
            a[mt][1] = ldb8(act + 131072 + o);
            a[mt][2] = ldb8(act + 262144 + o);
          }
          #pragma unroll
          for (int ct = 0; ct < 4; ++ct) {
            const int fb = (kcl * 4 + ct) * 2;
            bf16x8 w0 = *(const bf16x8*)&ldsw[(size_t)fb * 512 + l * 8];
            bf16x8 w1 = *(const bf16x8*)&ldsw[(size_t)(fb + 1) * 512 + l * 8];
            size_t f = (size_t)((4 * kq + kcl) * 4 + ct);
            bf16x8 w2 = ldb8(w2bH + f * 512 + l * 8);
            MM6(acc[0][ct], a[0][0], a[0][1], a[0][2], w0, w1, w2);
            MM6(acc[1][ct], a[1][0], a[1][1], a[1][2], w0, w1, w2);
          }
        }
        float* PC_ = ws + PCC;
        #pragma unroll
        for (int mt = 0; mt < 2; ++mt)
          #pragma unroll
          for (int ct = 0; ct < 4; ++ct)
            #pragma unroll
            for (int r = 0; r < 4; ++r) {
              int brow = (mtb + mt) * 16 + lq * 4 + r;
              int c = ct * 16 + lm;
              PC_[(size_t)kq * 16384 + (size_t)brow * 64 + c] = acc[mt][ct][r];
            }
      }
    }

    gridbar(bar, &bgen);

    // ============ phase 2: reduce + gates + streaming heads ============
    {
      const int gtid = blk * 512 + tid;
      for (int it = gtid; it < 278528; it += NTHR) {
        if (it < 131072) {
          if (s >= 1 && s <= 256) {
            const int b = it >> 9, h = it & 511;
            const float* PB = ws + PB1;
            float pr = 0.f, pz = 0.f, pni = 0.f, pnh = 0.f;
            #pragma unroll
            for (int kq = 0; kq < 8; ++kq) {
              const size_t base = (size_t)(kq * 3) * 131072 + (size_t)b * 512 + h;
              pr += PB[base]; pz += PB[base + 131072];
              float gn = PB[base + 262144];
              if (kq < 4) pni += gn; else pnh += gn;
            }
            const float rr = pr + b_ih1[h] + b_hh1[h];
            const float zz = pz + b_ih1[512 + h] + b_hh1[512 + h];
            const float ni = pni + b_ih1[1024 + h];
            const float nh = pnh + b_hh1[1024 + h];
            const float rg = sigmoidf_(rr), zg = sigmoidf_(zz);
            const float n = tanhf(ni + rg * nh);
            const float hold = ws[H1F + (size_t)(s & 1) * 131072 + (size_t)b * 512 + h];
            const float hnew = (1.f - zg) * n + zg * hold;
            ws[H1F + (size_t)((s - 1) & 1) * 131072 + (size_t)b * 512 + h] = hnew;
            ushort_t* cur = h1sB + (size_t)((s - 1) & 1) * 393216 + (size_t)b * 512 + h;
            __bf16 t0 = (__bf16)hnew; float r1 = hnew - (float)t0;
            __bf16 t1 = (__bf16)r1;  float r2 = r1 - (float)t1;
            cur[0] = __builtin_bit_cast(ushort_t, t0);
            cur[131072] = __builtin_bit_cast(ushort_t, t1);
            cur[262144] = __builtin_bit_cast(ushort_t, (__bf16)r2);
          }
        } else if (it < 262144) {
          if (s <= 255) {
            const int e = it - 131072, b = e >> 9, h = e & 511;
            const float* PA = ws + PA0;
            float pr = 0.f, pz = 0.f, pnh = 0.f;
            #pragma unroll
            for (int kq = 0; kq < 6; ++kq) {
              const size_t base = (size_t)(kq * 3) * 131072 + (size_t)b * 512 + h;
              pr += PA[base]; pz += PA[base + 131072]; pnh += PA[base + 262144];
            }
            const float niz = PA[(size_t)18 * 131072 + (size_t)b * 512 + h];
            const float* ac = ws + ACC0 + (size_t)b * 1536;
            const float rr = pr + ac[h] + b_hh0[h];
            const float zz = pz + ac[512 + h] + b_hh0[512 + h];
            const float ni = niz + ac[1024 + h];
            const float nh = pnh + b_hh0[1024 + h];
            const float rg = sigmoidf_(rr), zg = sigmoidf_(zz);
            const float n = tanhf(ni + rg * nh);
            const float hold = ws[H0F + (size_t)((s + 1) & 1) * 131072 + (size_t)b * 512 + h];
            const float hnew = (1.f - zg) * n + zg * hold;
            ws[H0F + (size_t)(s & 1) * 131072 + (size_t)b * 512 + h] = hnew;
            ushort_t* cur = h0sB + (size_t)(s & 1) * 393216 + (size_t)b * 512 + h;
            __bf16 t0 = (__bf16)hnew; float r1 = hnew - (float)t0;
            __bf16 t1 = (__bf16)r1;  float r2 = r1 - (float)t1;
            cur[0] = __builtin_bit_cast(ushort_t, t0);
            cur[131072] = __builtin_bit_cast(ushort_t, t1);
            cur[262144] = __builtin_bit_cast(ushort_t, (__bf16)r2);
          }
        } else {
          if (s >= 2) {
            const int hi = it - 262144;
            const int b = hi >> 6;
            const int sl = hi & 63;          // == lane (alignment verified: offsets mod 64 == 0)
            const int t = s - 2;
            const unsigned idx = (unsigned)(b * 256 + t);
            const int col = (sl < 40) ? sl : sl - 4;
            float logit = 0.f;
            if ((sl < 36 || sl >= 40) && col < 60) {
              const float* PC_ = ws + PCC;
              const size_t o = (size_t)b * 64 + col;
              float sum = PC_[o] + PC_[16384 + o] + PC_[32768 + o] + PC_[49152 + o];
              logit = sum + head_bias(hp, col);
            }
            // visit mask chain (lane 1)
            float ok = 0.f;
            if (sl == 1) {
              const float pv = sigmoidf_(logit);
              const float uv = rng_u01(ky.kv0, ky.kv1, idx);
              ok = (t == 0) ? 1.f : ((uv < pv) ? st_v : 0.f);
              st_v = ok;
            }
            const float mask = __shfl(ok, 1, 64);
            if (sl == 0) {
              const float dt = fmaxf(logit, 0.f) + log1pf(expf(-fabsf(logit)));
              st_cum += dt;
              out[O_VTIME + idx] = st_cum;     // unnormalized; vnorm_k divides later
            }
            if (sl == 1) out[O_VMASK + idx] = mask;
            if (sl >= 2 && sl < 34) out[O_TCONT + (size_t)idx * 32 + (sl - 2)] = logit * mask;
            if (sl == 34) {
              const float hz = sigmoidf_(logit);
              const float u = rng_u01(ky.ki00, ky.ki01, idx);
              st_i0 = fmaxf(st_i0, (u < hz) ? 1.f : 0.f);
              out[O_IRR0 + (size_t)idx * 2]     = (1.f - st_i0) * mask;
              out[O_IRR0 + (size_t)idx * 2 + 1] = st_i0 * mask;
            }
            if (sl == 35) {
              const float hz = sigmoidf_(logit);
              const float u = rng_u01(ky.ki10, ky.ki11, idx);
              st_i1 = fmaxf(st_i1, (u < hz) ? 1.f : 0.f);
              out[O_IRR1 + (size_t)idx * 2]     = (1.f - st_i1) * mask;
              out[O_IRR1 + (size_t)idx * 2 + 1] = st_i1 * mask;
            }
            // cat0: lanes 40..47 (xor-closed group)
            {
              const int j = sl - 40;
              float u = 0.f;
              if (sl >= 40 && sl < 48) u = rng_u01(ky.kc00, ky.kc01, idx * 8u + (unsigned)j);
              const float uu = fmaxf(1e-9f, u + 1e-9f);
              float x = logit - logf(-logf(uu));
              float m = x;
              m = fmaxf(m, __shfl_xor(m, 1, 64));
              m = fmaxf(m, __shfl_xor(m, 2, 64));
              m = fmaxf(m, __shfl_xor(m, 4, 64));
              float ex = expf(x - m);
              float ssum = ex;
              ssum += __shfl_xor(ssum, 1, 64);
              ssum += __shfl_xor(ssum, 2, 64);
              ssum += __shfl_xor(ssum, 4, 64);
              float y = ex / ssum;
              float by = y; int bj = j;
              #pragma unroll
              for (int d = 1; d <= 4; d <<= 1) {
                float oy = __shfl_xor(by, d, 64); int oj = __shfl_xor(bj, d, 64);
                if (oy > by || (oy == by && oj < bj)) { by = oy; bj = oj; }
              }
              if (sl >= 40 && sl < 48)
                out[O_CAT0 + (size_t)idx * 8 + j] = (j == bj) ? ((1.f + y) - y) * mask : 0.f;
            }
            // cat1: lanes 48..63
            {
              const int j = sl - 48;
              float u = 0.f;
              if (sl >= 48) u = rng_u01(ky.kc10, ky.kc11, idx * 16u + (unsigned)j);
              const float uu = fmaxf(1e-9f, u + 1e-9f);
              float x = logit - logf(-logf(uu));
              float m = x;
              m = fmaxf(m, __shfl_xor(m, 1, 64));
              m = fmaxf(m, __shfl_xor(m, 2, 64));
              m = fmaxf(m, __shfl_xor(m, 4, 64));
              m = fmaxf(m, __shfl_xor(m, 8, 64));
              float ex = expf(x - m);
              float ssum = ex;
              ssum += __shfl_xor(ssum, 1, 64);
              ssum += __shfl_xor(ssum, 2, 64);
              ssum += __shfl_xor(ssum, 4, 64);
              ssum += __shfl_xor(ssum, 8, 64);
              float y = ex / ssum;
              float by = y; int bj = j;
              #pragma unroll
              for (int d = 1; d <= 8; d <<= 1) {
                float oy = __shfl_xor(by, d, 64); int oj = __shfl_xor(bj, d, 64);
                if (oy > by || (oy == by && oj < bj)) { by = oy; bj = oj; }
              }
              if (sl >= 48)
                out[O_CAT1 + (size_t)idx * 16 + j] = (j == bj) ? ((1.f + y) - y) * mask : 0.f;
            }
          }
        }
      }
    }

    gridbar(bar, &bgen);
  }
}

// ---------------- static heads (unchanged)
__global__ __launch_bounds__(64) void static_heads_k(const float* __restrict__ sh_buf,
    const float* __restrict__ scont_w, const float* __restrict__ scont_b,
    const float* __restrict__ scat_w, const float* __restrict__ scat_b,
    float* __restrict__ out, unsigned ks0, unsigned ks1)
{
  __shared__ float hrow[512];
  __shared__ float xl[10];
  __shared__ float yv[10];
  __shared__ int argsh;
  int b = blockIdx.x, tid = threadIdx.x;
  const float* hr = sh_buf + (size_t)b * 512;
  for (int i = tid; i < 512; i += 64) hrow[i] = hr[i];
  __syncthreads();
  if (tid < 16) {
    float a = 0.f;
    const float* w = scont_w + (size_t)tid * 512;
    for (int k = 0; k < 512; ++k) a += hrow[k] * w[k];
    out[O_SCONT + (size_t)b * 16 + tid] = a + scont_b[tid];
  }
  if (tid < 10) {
    float a = 0.f;
    const float* w = scat_w + (size_t)tid * 512;
    for (int k = 0; k < 512; ++k) a += hrow[k] * w[k];
    a += scat_b[tid];
    float u = rng_u01(ks0, ks1, (unsigned)(b * 10 + tid));
    u = fmaxf(1e-9f, u + 1e-9f);
    float g = -logf(-logf(u));
    xl[tid] = a + g;
  }
  __syncthreads();
  if (tid == 0) {
    float m = xl[0];
    for (int c = 1; c < 10; ++c) m = fmaxf(m, xl[c]);
    float ssum = 0.f;
    for (int c = 0; c < 10; ++c) { yv[c] = expf(xl[c] - m); ssum += yv[c]; }
    int arg = 0; float best = -1.0f;
    for (int c = 0; c < 10; ++c) { yv[c] = yv[c] / ssum; if (yv[c] > best) { best = yv[c]; arg = c; } }
    argsh = arg;
  }
  __syncthreads();
  if (tid < 10) {
    float y = yv[tid];
    out[O_SCAT + (size_t)b * 10 + tid] = (tid == argsh) ? ((1.0f + y) - y) : 0.0f;
  }
}

// ---------------- vtime normalization (cumsum stored unnormalized)
__global__ __launch_bounds__(256) void vnorm_k(float* __restrict__ out) {
  int b = blockIdx.x, t = threadIdx.x;
  float denom = out[O_VTIME + (size_t)b * 256 + 255] + 1e-8f;
  float v = out[O_VTIME + (size_t)b * 256 + t];
  __syncthreads();
  out[O_VTIME + (size_t)b * 256 + t] = v / denom;
}

// ---------------- host entry
extern "C" void kernel_launch(void* const* d_in, const int* in_sizes, int n_in,
                              void* d_out, int out_size, void* d_ws, size_t ws_size,
                              hipStream_t stream)
{
  (void)in_sizes; (void)n_in; (void)out_size; (void)ws_size;
  const float* z_static   = (const float*)d_in[0];
  const float* z_temporal = (const float*)d_in[1];
  const float* fc1_w = (const float*)d_in[2];
  const float* fc1_b = (const float*)d_in[3];
  const float* fc2_w = (const float*)d_in[4];
  const float* fc2_b = (const float*)d_in[5];
  const float* w_ih0 = (const float*)d_in[6];
  const float* w_hh0 = (const float*)d_in[7];
  const float* b_ih0 = (const float*)d_in[8];
  const float* b_hh0 = (const float*)d_in[9];
  const float* w_ih1 = (const float*)d_in[10];
  const float* w_hh1 = (const float*)d_in[11];
  const float* b_ih1 = (const float*)d_in[12];
  const float* b_hh1 = (const float*)d_in[13];
  const float* time_w = (const float*)d_in[14];
  const float* time_b = (const float*)d_in[15];
  const float* visit_w = (const float*)d_in[16];
  const float* visit_b = (const float*)d_in[17];
  const float* tcont_w = (const float*)d_in[18];
  const float* tcont_b = (const float*)d_in[19];
  const float* irr0_w = (const float*)d_in[20];
  const float* irr0_b = (const float*)d_in[21];
  const float* irr1_w = (const float*)d_in[22];
  const float* irr1_b = (const float*)d_in[23];
  const float* cat0_w = (const float*)d_in[24];
  const float* cat0_b = (const float*)d_in[25];
  const float* cat1_w = (const float*)d_in[26];
  const float* cat1_b = (const float*)d_in[27];
  const float* scont_w = (const float*)d_in[28];
  const float* scont_b = (const float*)d_in[29];
  const float* scat_w = (const float*)d_in[30];
  const float* scat_b = (const float*)d_in[31];
  float* ws = (float*)d_ws;
  float* out = (float*)d_out;

  ushort_t* ws01 = (ushort_t*)(ws + PREG);
  ushort_t* w2b  = (ushort_t*)(ws + W2B);

  // static-path transposes (overlaid in PREG; consumed by gemms BEFORE arranges overwrite)
  transpose_k<<<dim3(4, 16), 256, 0, stream>>>(fc1_w, ws + FC1T, 512, 128, 128, 512);
  transpose_k<<<dim3(16, 16), 256, 0, stream>>>(fc2_w, ws + FC2T, 512, 512, 512, 512);
  transpose_k<<<dim3(16, 48), 256, 0, stream>>>(w_ih0 + 64, ws + WIS, 1536, 512, 576, 1536);
  hgather_k<<<64, 128, 0, stream>>>(time_w, visit_w, tcont_w, irr0_w, irr1_w, cat0_w, cat1_w, ws + WTH);

  gemm_k<<<8 * 16, 128, 0, stream>>>(z_static, ws + FC1T, fc1_b, ws + HID, 256, 128, 512, 1);
  gemm_k<<<8 * 16, 128, 0, stream>>>(ws + HID, ws + FC2T, fc2_b, ws + SHH, 256, 512, 512, 0);
  gemm_k<<<8 * 48, 128, 0, stream>>>(ws + SHH, ws + WIS, b_ih0, ws + ACC0, 256, 512, 1536, 0);

  // arranged weights: s0/s1 staging planes (overwrite FC/WIS region) + compact w2 planes
  arrangeB1_k<<<(32 * 32 * 3 * 64 + 255) / 256, 256, 0, stream>>>(w_ih1, w_hh1, ws01, w2b);
  arrangeA0_k<<<(18 * 32 * 3 * 64 + 255) / 256, 256, 0, stream>>>(w_hh0, w_ih0,
      ws01 + WS01A_OFS, w2b + W2BA_OFS);
  arrangeH_k<<<(16 * 4 * 64 + 255) / 256, 256, 0, stream>>>(ws + WTH,
      ws01 + WS01H_OFS, w2b + W2BH_OFS);

  // RNG keys: key(42)=(0,42); 6 children (partitionable fold-in)
  unsigned kk[6][2];
  for (int i = 0; i < 6; ++i) tf2x32(0u, 42u, 0u, (unsigned)i, &kk[i][0], &kk[i][1]);

  static_heads_k<<<256, 64, 0, stream>>>(ws + SHH, scont_w, scont_b, scat_w, scat_b, out,
                                         kk[5][0], kk[5][1]);

  // zero init: f32 states parity 1, split planes parity 1, barrier
  hipMemsetAsync((void*)(ws + H0F + 131072), 0, 131072 * sizeof(float), stream);
  hipMemsetAsync((void*)(ws + H1F + 131072), 0, 131072 * sizeof(float), stream);
  hipMemsetAsync((void*)((ushort_t*)(ws + H0S) + 393216), 0, 393216 * sizeof(ushort_t), stream);
  hipMemsetAsync((void*)((ushort_t*)(ws + H1S) + 393216), 0, 393216 * sizeof(ushort_t), stream);
  hipMemsetAsync((void*)(ws + BARO), 0, 64, stream);

  HeadPtrs hp{time_b, visit_b, tcont_b, irr0_b, irr1_b, cat0_b, cat1_b};
  Keys ky{kk[0][0], kk[0][1], kk[1][0], kk[1][1], kk[2][0], kk[2][1],
          kk[3][0], kk[3][1], kk[4][0], kk[4][1]};

  persistent_k<<<NBLK, 512, 0, stream>>>(z_temporal, b_hh0, b_ih1, b_hh1, hp, ky, ws, out);

  vnorm_k<<<256, 256, 0, stream>>>(out);
}

// Round 4
// 7534.925 us; speedup vs baseline: 5.3982x; 5.3982x over previous
//
#include <hip/hip_runtime.h>
#include <hip/hip_bf16.h>
#include <cstdint>
#include <cstddef>

#define RNG_PART 1

typedef __bf16 bf16x8 __attribute__((ext_vector_type(8)));
typedef float f32x4 __attribute__((ext_vector_type(4)));
typedef unsigned short ushort_t;

// ---------------- sizes: B=256, T=256, ZS=128, ZT=64, H=512, 3H=1536

// ---------------- workspace layout (float offsets)
static constexpr size_t ACC0 = 0;                  // [256][1536] f32 static part of xp0 (+b_ih0)
static constexpr size_t SHH  = 393216;             // [256][512] static_h
static constexpr size_t HID  = 524288;             // [256][512] fc1 hidden
static constexpr size_t H0F  = 655360;             // [2][256][512] f32 ping-pong h0
static constexpr size_t H1F  = 917504;             // [2][256][512] f32 ping-pong h1
static constexpr size_t LOGB = 1179648;            // [256][256][64] f32 head logits
static constexpr size_t WTH  = 5373952;            // [512][64] f32 gathered head weights
// bf16 regions (float offsets; 2 bf16 per float)
static constexpr size_t H0S  = 5406720;            // [2][3][256][512] bf16 splits of h0
static constexpr size_t H1S  = 5799936;            // [2][3][256][512] bf16 splits of h1
static constexpr size_t WB1  = 6193152;            // [32][32][3][3][64][8] bf16 arranged L1 weights
static constexpr size_t WA0  = 8552448;            // [18][32][3][3][64][8] bf16 arranged L0 weights
static constexpr size_t WH   = 9879552;            // [16][4][3][64][8] bf16 arranged head weights
// aliases into LOGB (consumed before step loop writes LOGB)
static constexpr size_t FC1T = LOGB;               // [128][512]
static constexpr size_t FC2T = LOGB + 65536;       // [512][512]
static constexpr size_t WIS  = FC2T + 262144;      // [512][1536] w_ih0[:,64:]^T

// ---------------- output layout (float offsets)
static constexpr size_t O_SCONT = 0;
static constexpr size_t O_SCAT  = 4096;
static constexpr size_t O_TCONT = 6656;
static constexpr size_t O_IRR0  = 2103808;
static constexpr size_t O_IRR1  = 2234880;
static constexpr size_t O_CAT0  = 2365952;
static constexpr size_t O_CAT1  = 2890240;
static constexpr size_t O_VMASK = 3938816;
static constexpr size_t O_VTIME = 4004352;

// ---------------- threefry2x32-20
__host__ __device__ inline void tf2x32(unsigned k0, unsigned k1, unsigned x0, unsigned x1,
                                       unsigned* o0, unsigned* o1) {
  unsigned ks2 = k0 ^ k1 ^ 0x1BD11BDAu;
#define TFR(r) { x0 += x1; x1 = (x1 << (r)) | (x1 >> (32 - (r))); x1 ^= x0; }
  x0 += k0; x1 += k1;
  TFR(13) TFR(15) TFR(26) TFR(6)
  x0 += k1; x1 += ks2 + 1u;
  TFR(17) TFR(29) TFR(16) TFR(24)
  x0 += ks2; x1 += k0 + 2u;
  TFR(13) TFR(15) TFR(26) TFR(6)
  x0 += k0; x1 += k1 + 3u;
  TFR(17) TFR(29) TFR(16) TFR(24)
  x0 += k1; x1 += ks2 + 4u;
  TFR(13) TFR(15) TFR(26) TFR(6)
  x0 += ks2; x1 += k0 + 5u;
#undef TFR
  *o0 = x0; *o1 = x1;
}

__device__ inline float rng_u01(unsigned k0, unsigned k1, unsigned idx) {
  unsigned o0, o1;
  tf2x32(k0, k1, 0u, idx, &o0, &o1);
  unsigned bits = o0 ^ o1;
  return __uint_as_float((bits >> 9) | 0x3f800000u) - 1.0f;
}

__device__ inline float sigmoidf_(float x) { return 1.0f / (1.0f + expf(-x)); }

// ---------------- tiled transpose: dst[k*dstStride + j] = src[j*srcStride + k]
__global__ __launch_bounds__(256) void transpose_k(const float* __restrict__ src, float* __restrict__ dst,
                                                   int J, int K, int srcStride, int dstStride) {
  __shared__ float tile[32][33];
  int kb = blockIdx.x * 32, jb = blockIdx.y * 32;
  int tx = threadIdx.x & 31, ty = threadIdx.x >> 5;
  #pragma unroll
  for (int r = 0; r < 4; ++r) {
    int j = jb + ty + r * 8, k = kb + tx;
    if (j < J && k < K) tile[ty + r * 8][tx] = src[(size_t)j * srcStride + k];
  }
  __syncthreads();
  #pragma unroll
  for (int r = 0; r < 4; ++r) {
    int k = kb + ty + r * 8, j = jb + tx;
    if (k < K && j < J) dst[(size_t)k * dstStride + j] = tile[tx][ty + r * 8];
  }
}

// ---------------- gather head weights into wtH[512][64] (cols 60..63 zero)
__global__ void hgather_k(const float* __restrict__ time_w, const float* __restrict__ visit_w,
                          const float* __restrict__ tcont_w, const float* __restrict__ irr0_w,
                          const float* __restrict__ irr1_w, const float* __restrict__ cat0_w,
                          const float* __restrict__ cat1_w, float* __restrict__ wtH) {
  int c = blockIdx.x;
  if (c >= 60) {
    for (int k = threadIdx.x; k < 512; k += blockDim.x) wtH[(size_t)k * 64 + c] = 0.0f;
    return;
  }
  const float* src;
  if (c == 0) src = time_w;
  else if (c == 1) src = visit_w;
  else if (c < 34) src = tcont_w + (size_t)(c - 2) * 512;
  else if (c == 34) src = irr0_w;
  else if (c == 35) src = irr1_w;
  else if (c < 44) src = cat0_w + (size_t)(c - 36) * 512;
  else src = cat1_w + (size_t)(c - 44) * 512;
  for (int k = threadIdx.x; k < 512; k += blockDim.x) wtH[(size_t)k * 64 + c] = src[k];
}

// ---------------- generic fp32 GEMM (pre-loop static path only)
__global__ __launch_bounds__(128) void gemm_k(const float* __restrict__ in, const float* __restrict__ wT,
                                              const float* __restrict__ bias, float* __restrict__ out,
                                              int M, int K, int J, int relu) {
  __shared__ float ibuf[64][34];
  __shared__ float wbuf[64][36];
  int jt = blockIdx.x % (J >> 5), mt = blockIdx.x / (J >> 5);
  int m0 = mt * 32, j0 = jt * 32;
  int tid = threadIdx.x;
  int mq = tid & 15, jq = tid >> 4;
  float acc[2][4] = {{0.f, 0.f, 0.f, 0.f}, {0.f, 0.f, 0.f, 0.f}};
  for (int kc = 0; kc < K; kc += 64) {
    __syncthreads();
    #pragma unroll
    for (int i = 0; i < 16; ++i) {
      int lin = i * 128 + tid;
      int k = lin & 63, m = lin >> 6;
      ibuf[k][m] = in[(size_t)(m0 + m) * K + kc + k];
    }
    #pragma unroll
    for (int i = 0; i < 16; ++i) {
      int lin = i * 128 + tid;
      int c = lin & 31, k = lin >> 5;
      wbuf[k][c] = wT[(size_t)(kc + k) * J + j0 + c];
    }
    __syncthreads();
    #pragma unroll 8
    for (int k = 0; k < 64; ++k) {
      float i0 = ibuf[k][2 * mq], i1 = ibuf[k][2 * mq + 1];
      const float4 w = *(const float4*)&wbuf[k][4 * jq];
      acc[0][0] += i0 * w.x; acc[0][1] += i0 * w.y; acc[0][2] += i0 * w.z; acc[0][3] += i0 * w.w;
      acc[1][0] += i1 * w.x; acc[1][1] += i1 * w.y; acc[1][2] += i1 * w.z; acc[1][3] += i1 * w.w;
    }
  }
  #pragma unroll
  for (int mi = 0; mi < 2; ++mi)
    #pragma unroll
    for (int ji = 0; ji < 4; ++ji) {
      int j = j0 + 4 * jq + ji;
      float v = acc[mi][ji] + bias[j];
      if (relu) v = fmaxf(v, 0.0f);
      out[(size_t)(m0 + 2 * mq + mi) * J + j] = v;
    }
}

// ---------------- weight arrangement into MFMA-fragment order, 3-way bf16 split
__device__ inline void split3_store(float v, ushort_t* p0, ushort_t* p1, ushort_t* p2) {
  __bf16 t0 = (__bf16)v; float r1 = v - (float)t0;
  __bf16 t1 = (__bf16)r1; float r2 = r1 - (float)t1;
  __bf16 t2 = (__bf16)r2;
  *p0 = __builtin_bit_cast(ushort_t, t0);
  *p1 = __builtin_bit_cast(ushort_t, t1);
  *p2 = __builtin_bit_cast(ushort_t, t2);
}

__global__ __launch_bounds__(256) void arrangeB1_k(const float* __restrict__ w_ih1,
                                                   const float* __restrict__ w_hh1,
                                                   ushort_t* __restrict__ dst) {
  int id = blockIdx.x * 256 + threadIdx.x;          // (kc,ht,g,l): 32*32*3*64
  if (id >= 32 * 32 * 3 * 64) return;
  int l = id & 63; int rest = id >> 6;
  int g = rest % 3; rest /= 3;
  int ht = rest & 31; int kc = rest >> 5;
  int n = g * 512 + ht * 16 + (l & 15);
  int kbase = kc * 32 + (l >> 4) * 8;
  size_t ob = (size_t)((kc * 32 + ht) * 3 + g) * 1536 + (size_t)l * 8;
  #pragma unroll
  for (int j = 0; j < 8; ++j) {
    int k = kbase + j;
    float v = (k < 512) ? w_ih1[(size_t)n * 512 + k] : w_hh1[(size_t)n * 512 + (k - 512)];
    split3_store(v, dst + ob + j, dst + ob + 512 + j, dst + ob + 1024 + j);
  }
}

__global__ __launch_bounds__(256) void arrangeA0_k(const float* __restrict__ w_hh0,
                                                   const float* __restrict__ w_ih0,
                                                   ushort_t* __restrict__ dst) {
  int id = blockIdx.x * 256 + threadIdx.x;          // (kc,ht,g,l): 18*32*3*64
  if (id >= 18 * 32 * 3 * 64) return;
  int l = id & 63; int rest = id >> 6;
  int g = rest % 3; rest /= 3;
  int ht = rest & 31; int kc = rest >> 5;
  int n = g * 512 + ht * 16 + (l & 15);
  int kbase = kc * 32 + (l >> 4) * 8;
  size_t ob = (size_t)((kc * 32 + ht) * 3 + g) * 1536 + (size_t)l * 8;
  #pragma unroll
  for (int j = 0; j < 8; ++j) {
    int k = kbase + j;
    float v = (k < 512) ? w_hh0[(size_t)n * 512 + k] : w_ih0[(size_t)n * 576 + (k - 512)];
    split3_store(v, dst + ob + j, dst + ob + 512 + j, dst + ob + 1024 + j);
  }
}

__global__ __launch_bounds__(256) void arrangeH_k(const float* __restrict__ wtH,
                                                  ushort_t* __restrict__ dst) {
  int id = blockIdx.x * 256 + threadIdx.x;          // (kc,ct,l): 16*4*64
  if (id >= 16 * 4 * 64) return;
  int l = id & 63; int rest = id >> 6;
  int ct = rest & 3; int kc = rest >> 2;
  int c = ct * 16 + (l & 15);
  int kbase = kc * 32 + (l >> 4) * 8;
  size_t ob = (size_t)(kc * 4 + ct) * 1536 + (size_t)l * 8;
  #pragma unroll
  for (int j = 0; j < 8; ++j) {
    float v = wtH[(size_t)(kbase + j) * 64 + c];
    split3_store(v, dst + ob + j, dst + ob + 512 + j, dst + ob + 1024 + j);
  }
}

// ---------------- MFMA helpers: 6-product split accumulation (fp32-accurate)
__device__ inline bf16x8 ldb8(const ushort_t* p) { return *reinterpret_cast<const bf16x8*>(p); }

#define MFMA_(A, W, C) __builtin_amdgcn_mfma_f32_16x16x32_bf16((A), (W), (C), 0, 0, 0)

__device__ inline f32x4 mm6(f32x4 acc, bf16x8 a0, bf16x8 a1, bf16x8 a2, const ushort_t* wb) {
  bf16x8 w0 = ldb8(wb), w1 = ldb8(wb + 512), w2 = ldb8(wb + 1024);
  acc = MFMA_(a0, w0, acc); acc = MFMA_(a0, w1, acc); acc = MFMA_(a1, w0, acc);
  acc = MFMA_(a1, w1, acc); acc = MFMA_(a0, w2, acc); acc = MFMA_(a2, w0, acc);
  return acc;
}

struct HeadPtrs {
  const float *time_b, *visit_b, *tcont_b, *irr0_b, *irr1_b, *cat0_b, *cat1_b;
};

__device__ inline float head_bias(const HeadPtrs& hp, int c) {
  if (c == 0) return hp.time_b[0];
  if (c == 1) return hp.visit_b[0];
  if (c < 34) return hp.tcont_b[c - 2];
  if (c == 34) return hp.irr0_b[0];
  if (c == 35) return hp.irr1_b[0];
  if (c < 44) return hp.cat0_b[c - 36];
  return hp.cat1_b[c - 44];
}

// ---------------- fused per-step MFMA kernel, K-split x2 with in-block LDS reduction
// blk in [0,512): even = job B (h1 update, step s-1), odd = job A (h0 update, step s)
//   idx = blk>>1: ht = idx&31 (XCD-aligned weight slice), bt = idx>>5 (16 batch tiles)
//   4 waves: mt = wv&1 (which 16-row M-tile), kh = wv>>1 (which K half)
// blk in [512,520): job C (head logits for t = s-2), bt = blk-512 (32 rows each)
__global__ __launch_bounds__(256, 2) void step_k(int s,
    const float* __restrict__ z_temporal,
    const float* __restrict__ b_hh0,
    const float* __restrict__ b_ih1, const float* __restrict__ b_hh1,
    float* __restrict__ ws, HeadPtrs hp)
{
  __shared__ f32x4 red[2][4][64];   // [mt][vec][lane] = 8 KB
  const int blk = blockIdx.x, tid = threadIdx.x;
  const int wv = tid >> 6, l = tid & 63, lm = l & 15, lq = l >> 4;
  const int mt = wv & 1, kh = wv >> 1;
  const ushort_t* h0sAll = (const ushort_t*)(ws + H0S);
  const ushort_t* h1sAll = (const ushort_t*)(ws + H1S);

  if (blk < 512) {
    const int job = blk & 1;
    const int idx = blk >> 1;
    const int ht = idx & 31, bt = idx >> 5;
    const int b0 = bt * 32 + mt * 16;
    const int hc = ht * 16;
    const size_t arow = (size_t)(b0 + lm) * 512 + (size_t)lq * 8;

    if (job == 0) {
      // ---- job B: h1_{s-1} = GRUcell1(h0_{s-1}, h1_{s-2}); s in [1,256]
      if (s < 1 || s > 256) return;
      const ushort_t* act = (kh == 0) ? (h0sAll + (size_t)((s - 1) & 1) * 393216)
                                      : (h1sAll + (size_t)(s & 1) * 393216);
      const ushort_t* wbB = (const ushort_t*)(ws + WB1) + (size_t)ht * 4608 + (size_t)l * 8
                            + (size_t)(kh * 16) * 147456;
      f32x4 vr = {}, vz = {}, vn = {};
      #pragma unroll 2
      for (int kcl = 0; kcl < 16; ++kcl) {
        const size_t ao = arow + (size_t)kcl * 32;
        bf16x8 a0 = ldb8(act + ao);
        bf16x8 a1 = ldb8(act + 131072 + ao);
        bf16x8 a2 = ldb8(act + 262144 + ao);
        const ushort_t* wb = wbB + (size_t)kcl * 147456;
        vr = mm6(vr, a0, a1, a2, wb);
        vz = mm6(vz, a0, a1, a2, wb + 1536);
        vn = mm6(vn, a0, a1, a2, wb + 3072);
      }
      if (kh == 1) { red[mt][0][l] = vr; red[mt][1][l] = vz; red[mt][2][l] = vn; }
      __syncthreads();
      if (kh == 0) {
        const f32x4 r4 = vr + red[mt][0][l];
        const f32x4 z4 = vz + red[mt][1][l];
        const f32x4 nh4 = red[mt][2][l];
        const float* h1f_old = ws + H1F + (size_t)(s & 1) * 131072;
        float* h1f_cur = ws + H1F + (size_t)((s - 1) & 1) * 131072;
        ushort_t* h1s_cur = (ushort_t*)(ws + H1S) + (size_t)((s - 1) & 1) * 393216;
        const int h = hc + lm;
        #pragma unroll
        for (int r = 0; r < 4; ++r) {
          const int b = b0 + lq * 4 + r;
          const float rr = r4[r] + b_ih1[h] + b_hh1[h];
          const float zz = z4[r] + b_ih1[512 + h] + b_hh1[512 + h];
          const float ni = vn[r] + b_ih1[1024 + h];
          const float nh = nh4[r] + b_hh1[1024 + h];
          const float rg = sigmoidf_(rr), zg = sigmoidf_(zz);
          const float n = tanhf(ni + rg * nh);
          const float hold = h1f_old[(size_t)b * 512 + h];
          const float hnew = (1.0f - zg) * n + zg * hold;
          h1f_cur[(size_t)b * 512 + h] = hnew;
          __bf16 t0 = (__bf16)hnew; float r1 = hnew - (float)t0;
          __bf16 t1 = (__bf16)r1;   float r2 = r1 - (float)t1;
          const size_t ho = (size_t)b * 512 + h;
          h1s_cur[ho]          = __builtin_bit_cast(ushort_t, t0);
          h1s_cur[131072 + ho] = __builtin_bit_cast(ushort_t, t1);
          h1s_cur[262144 + ho] = __builtin_bit_cast(ushort_t, (__bf16)r2);
        }
      }
    } else {
      // ---- job A: h0_s = GRUcell0(z_s ++ static, h0_{s-1}); s in [0,255]
      if (s > 255) return;
      const ushort_t* act = h0sAll + (size_t)((s + 1) & 1) * 393216;
      const ushort_t* wbA = (const ushort_t*)(ws + WA0) + (size_t)ht * 4608 + (size_t)l * 8;
      f32x4 vr = {}, vz = {}, vn = {}, vni = {};
      const int nkc = kh ? 10 : 8;
      #pragma unroll 2
      for (int kcl = 0; kcl < nkc; ++kcl) {
        const int kcg = kh * 8 + kcl;
        bf16x8 a0, a1, a2;
        if (kcg < 16) {
          const size_t ao = arow + (size_t)kcg * 32;
          a0 = ldb8(act + ao);
          a1 = ldb8(act + 131072 + ao);
          a2 = ldb8(act + 262144 + ao);
        } else {
          const float* zp = z_temporal + ((size_t)(b0 + lm) * 256 + s) * 64 + (kcg - 16) * 32 + lq * 8;
          float4 q0 = *(const float4*)zp;
          float4 q1 = *(const float4*)(zp + 4);
          float vals[8] = {q0.x, q0.y, q0.z, q0.w, q1.x, q1.y, q1.z, q1.w};
          #pragma unroll
          for (int j = 0; j < 8; ++j) {
            float v = vals[j];
            __bf16 t0 = (__bf16)v; float r1 = v - (float)t0;
            __bf16 t1 = (__bf16)r1; float r2 = r1 - (float)t1;
            a0[j] = t0; a1[j] = t1; a2[j] = (__bf16)r2;
          }
        }
        const ushort_t* wb = wbA + (size_t)kcg * 147456;
        vr = mm6(vr, a0, a1, a2, wb);
        vz = mm6(vz, a0, a1, a2, wb + 1536);
        if (kcg < 16) vn  = mm6(vn,  a0, a1, a2, wb + 3072);
        else          vni = mm6(vni, a0, a1, a2, wb + 3072);
      }
      if (kh == 1) {
        red[mt][0][l] = vr; red[mt][1][l] = vz; red[mt][2][l] = vn; red[mt][3][l] = vni;
      }
      __syncthreads();
      if (kh == 0) {
        const f32x4 r4 = vr + red[mt][0][l];
        const f32x4 z4 = vz + red[mt][1][l];
        const f32x4 nh4 = vn + red[mt][2][l];
        const f32x4 ni4 = red[mt][3][l];
        const float* h0f_old = ws + H0F + (size_t)((s + 1) & 1) * 131072;
        float* h0f_cur = ws + H0F + (size_t)(s & 1) * 131072;
        ushort_t* h0s_cur = (ushort_t*)(ws + H0S) + (size_t)(s & 1) * 393216;
        const float* acc0 = ws + ACC0;
        const int h = hc + lm;
        #pragma unroll
        for (int r = 0; r < 4; ++r) {
          const int b = b0 + lq * 4 + r;
          const float* ac = acc0 + (size_t)b * 1536;
          const float rr = r4[r] + ac[h] + b_hh0[h];
          const float zz = z4[r] + ac[512 + h] + b_hh0[512 + h];
          const float ni = ni4[r] + ac[1024 + h];
          const float nh = nh4[r] + b_hh0[1024 + h];
          const float rg = sigmoidf_(rr), zg = sigmoidf_(zz);
          const float n = tanhf(ni + rg * nh);
          const float hold = h0f_old[(size_t)b * 512 + h];
          const float hnew = (1.0f - zg) * n + zg * hold;
          h0f_cur[(size_t)b * 512 + h] = hnew;
          __bf16 t0 = (__bf16)hnew; float r1 = hnew - (float)t0;
          __bf16 t1 = (__bf16)r1;   float r2 = r1 - (float)t1;
          const size_t ho = (size_t)b * 512 + h;
          h0s_cur[ho]          = __builtin_bit_cast(ushort_t, t0);
          h0s_cur[131072 + ho] = __builtin_bit_cast(ushort_t, t1);
          h0s_cur[262144 + ho] = __builtin_bit_cast(ushort_t, (__bf16)r2);
        }
      }
    }
  } else {
    // ---- job C: head logits for t = s-2 from h1_{s-2}; s in [2,257]
    if (s < 2) return;
    const int bt = blk - 512;
    const int b0 = bt * 32 + mt * 16;
    const int t = s - 2;
    const ushort_t* act = h1sAll + (size_t)(s & 1) * 393216;
    const ushort_t* wH = (const ushort_t*)(ws + WH) + (size_t)l * 8;
    const size_t arow = (size_t)(b0 + lm) * 512 + (size_t)lq * 8;
    f32x4 va[4] = {};
    #pragma unroll 2
    for (int kcl = 0; kcl < 8; ++kcl) {
      const int kc = kh * 8 + kcl;
      const size_t ao = arow + (size_t)kc * 32;
      bf16x8 a0 = ldb8(act + ao);
      bf16x8 a1 = ldb8(act + 131072 + ao);
      bf16x8 a2 = ldb8(act + 262144 + ao);
      #pragma unroll
      for (int ct = 0; ct < 4; ++ct)
        va[ct] = mm6(va[ct], a0, a1, a2, wH + (size_t)(kc * 4 + ct) * 1536);
    }
    if (kh == 1) {
      #pragma unroll
      for (int ct = 0; ct < 4; ++ct) red[mt][ct][l] = va[ct];
    }
    __syncthreads();
    if (kh == 0) {
      float* lg = ws + LOGB;
      #pragma unroll
      for (int ct = 0; ct < 4; ++ct) {
        const f32x4 v4 = va[ct] + red[mt][ct][l];
        const int c = ct * 16 + lm;
        if (c < 60) {
          const float bias = head_bias(hp, c);
          #pragma unroll
          for (int r = 0; r < 4; ++r) {
            const int b = b0 + lq * 4 + r;
            lg[((size_t)b * 256 + t) * 64 + c] = v4[r] + bias;
          }
        }
      }
    }
  }
}

// ---------------- static heads
__global__ __launch_bounds__(64) void static_heads_k(const float* __restrict__ sh_buf,
    const float* __restrict__ scont_w, const float* __restrict__ scont_b,
    const float* __restrict__ scat_w, const float* __restrict__ scat_b,
    float* __restrict__ out, unsigned ks0, unsigned ks1)
{
  __shared__ float hrow[512];
  __shared__ float xl[10];
  __shared__ float yv[10];
  __shared__ int argsh;
  int b = blockIdx.x, tid = threadIdx.x;
  const float* hr = sh_buf + (size_t)b * 512;
  for (int i = tid; i < 512; i += 64) hrow[i] = hr[i];
  __syncthreads();
  if (tid < 16) {
    float a = 0.f;
    const float* w = scont_w + (size_t)tid * 512;
    for (int k = 0; k < 512; ++k) a += hrow[k] * w[k];
    out[O_SCONT + (size_t)b * 16 + tid] = a + scont_b[tid];
  }
  if (tid < 10) {
    float a = 0.f;
    const float* w = scat_w + (size_t)tid * 512;
    for (int k = 0; k < 512; ++k) a += hrow[k] * w[k];
    a += scat_b[tid];
    float u = rng_u01(ks0, ks1, (unsigned)(b * 10 + tid));
    u = fmaxf(1e-9f, u + 1e-9f);
    float g = -logf(-logf(u));
    xl[tid] = a + g;
  }
  __syncthreads();
  if (tid == 0) {
    float m = xl[0];
    for (int c = 1; c < 10; ++c) m = fmaxf(m, xl[c]);
    float ssum = 0.f;
    for (int c = 0; c < 10; ++c) { yv[c] = expf(xl[c] - m); ssum += yv[c]; }
    int arg = 0; float best = -1.0f;
    for (int c = 0; c < 10; ++c) { yv[c] = yv[c] / ssum; if (yv[c] > best) { best = yv[c]; arg = c; } }
    argsh = arg;
  }
  __syncthreads();
  if (tid < 10) {
    float y = yv[tid];
    out[O_SCAT + (size_t)b * 10 + tid] = (tid == argsh) ? ((1.0f + y) - y) : 0.0f;
  }
}

// ---------------- final scans + sampling + emission
struct Keys { unsigned kv0, kv1, ki00, ki01, ki10, ki11, kc00, kc01, kc10, kc11; };

__global__ __launch_bounds__(256) void final_k(const float* __restrict__ ws, float* __restrict__ out, Keys ky)
{
  __shared__ float sh[256];
  __shared__ unsigned shu[256];
  int b = blockIdx.x, t = threadIdx.x;
  int idx = b * 256 + t;
  const float* lg = ws + LOGB + (size_t)idx * 64;
  float l0 = lg[0], l1 = lg[1], l34 = lg[34], l35 = lg[35];

  float dt = fmaxf(l0, 0.0f) + log1pf(expf(-fabsf(l0)));
  sh[t] = dt; __syncthreads();
  for (int off = 1; off < 256; off <<= 1) {
    float v = (t >= off) ? sh[t - off] : 0.0f;
    __syncthreads();
    sh[t] += v;
    __syncthreads();
  }
  float vt = sh[t];
  float denom = sh[255] + 1e-8f;
  out[O_VTIME + idx] = vt / denom;
  __syncthreads();

  float pv = sigmoidf_(l1);
  float uv = rng_u01(ky.kv0, ky.kv1, (unsigned)idx);
  shu[t] = (t == 0) ? 1u : (uv < pv ? 1u : 0u);
  __syncthreads();
  for (int off = 1; off < 256; off <<= 1) {
    unsigned v = (t >= off) ? shu[t - off] : 1u;
    __syncthreads();
    shu[t] &= v;
    __syncthreads();
  }
  float mask = (float)shu[t];
  out[O_VMASK + idx] = mask;
  __syncthreads();

  {
    float hz = sigmoidf_(l34);
    float u = rng_u01(ky.ki00, ky.ki01, (unsigned)idx);
    shu[t] = (u < hz) ? 1u : 0u;
    __syncthreads();
    for (int off = 1; off < 256; off <<= 1) {
      unsigned v = (t >= off) ? shu[t - off] : 0u;
      __syncthreads();
      shu[t] |= v;
      __syncthreads();
    }
    float st = (float)shu[t];
    out[O_IRR0 + (size_t)idx * 2]     = (1.0f - st) * mask;
    out[O_IRR0 + (size_t)idx * 2 + 1] = st * mask;
    __syncthreads();
  }
  {
    float hz = sigmoidf_(l35);
    float u = rng_u01(ky.ki10, ky.ki11, (unsigned)idx);
    shu[t] = (u < hz) ? 1u : 0u;
    __syncthreads();
    for (int off = 1; off < 256; off <<= 1) {
      unsigned v = (t >= off) ? shu[t - off] : 0u;
      __syncthreads();
      shu[t] |= v;
      __syncthreads();
    }
    float st = (float)shu[t];
    out[O_IRR1 + (size_t)idx * 2]     = (1.0f - st) * mask;
    out[O_IRR1 + (size_t)idx * 2 + 1] = st * mask;
  }

  #pragma unroll
  for (int c = 0; c < 32; ++c)
    out[O_TCONT + (size_t)idx * 32 + c] = lg[2 + c] * mask;

  {
    float x[8], y[8];
    float m = -1e30f;
    #pragma unroll
    for (int c = 0; c < 8; ++c) {
      float u = rng_u01(ky.kc00, ky.kc01, (unsigned)idx * 8u + c);
      u = fmaxf(1e-9f, u + 1e-9f);
      float g = -logf(-logf(u));
      x[c] = lg[36 + c] + g;
      m = fmaxf(m, x[c]);
    }
    float ssum = 0.f;
    #pragma unroll
    for (int c = 0; c < 8; ++c) { y[c] = expf(x[c] - m); ssum += y[c]; }
    int arg = 0; float best = -1.0f;
    #pragma unroll
    for (int c = 0; c < 8; ++c) { y[c] /= ssum; if (y[c] > best) { best = y[c]; arg = c; } }
    #pragma unroll
    for (int c = 0; c < 8; ++c)
      out[O_CAT0 + (size_t)idx * 8 + c] = (c == arg) ? ((1.0f + y[c]) - y[c]) * mask : 0.0f;
  }
  {
    float x[16], y[16];
    float m = -1e30f;
    #pragma unroll
    for (int c = 0; c < 16; ++c) {
      float u = rng_u01(ky.kc10, ky.kc11, (unsigned)idx * 16u + c);
      u = fmaxf(1e-9f, u + 1e-9f);
      float g = -logf(-logf(u));
      x[c] = lg[44 + c] + g;
      m = fmaxf(m, x[c]);
    }
    float ssum = 0.f;
    #pragma unroll
    for (int c = 0; c < 16; ++c) { y[c] = expf(x[c] - m); ssum += y[c]; }
    int arg = 0; float best = -1.0f;
    #pragma unroll
    for (int c = 0; c < 16; ++c) { y[c] /= ssum; if (y[c] > best) { best = y[c]; arg = c; } }
    #pragma unroll
    for (int c = 0; c < 16; ++c)
      out[O_CAT1 + (size_t)idx * 16 + c] = (c == arg) ? ((1.0f + y[c]) - y[c]) * mask : 0.0f;
  }
}

// ---------------- host entry
extern "C" void kernel_launch(void* const* d_in, const int* in_sizes, int n_in,
                              void* d_out, int out_size, void* d_ws, size_t ws_size,
                              hipStream_t stream)
{
  (void)in_sizes; (void)n_in; (void)out_size; (void)ws_size;
  const float* z_static   = (const float*)d_in[0];
  const float* z_temporal = (const float*)d_in[1];
  const float* fc1_w = (const float*)d_in[2];
  const float* fc1_b = (const float*)d_in[3];
  const float* fc2_w = (const float*)d_in[4];
  const float* fc2_b = (const float*)d_in[5];
  const float* w_ih0 = (const float*)d_in[6];
  const float* w_hh0 = (const float*)d_in[7];
  const float* b_ih0 = (const float*)d_in[8];
  const float* b_hh0 = (const float*)d_in[9];
  const float* w_ih1 = (const float*)d_in[10];
  const float* w_hh1 = (const float*)d_in[11];
  const float* b_ih1 = (const float*)d_in[12];
  const float* b_hh1 = (const float*)d_in[13];
  const float* time_w = (const float*)d_in[14];
  const float* time_b = (const float*)d_in[15];
  const float* visit_w = (const float*)d_in[16];
  const float* visit_b = (const float*)d_in[17];
  const float* tcont_w = (const float*)d_in[18];
  const float* tcont_b = (const float*)d_in[19];
  const float* irr0_w = (const float*)d_in[20];
  const float* irr0_b = (const float*)d_in[21];
  const float* irr1_w = (const float*)d_in[22];
  const float* irr1_b = (const float*)d_in[23];
  const float* cat0_w = (const float*)d_in[24];
  const float* cat0_b = (const float*)d_in[25];
  const float* cat1_w = (const float*)d_in[26];
  const float* cat1_b = (const float*)d_in[27];
  const float* scont_w = (const float*)d_in[28];
  const float* scont_b = (const float*)d_in[29];
  const float* scat_w = (const float*)d_in[30];
  const float* scat_b = (const float*)d_in[31];
  float* ws = (float*)d_ws;
  float* out = (float*)d_out;

  // static-path transposes (aliased into LOGB region, consumed pre-loop)
  transpose_k<<<dim3(4, 16), 256, 0, stream>>>(fc1_w, ws + FC1T, 512, 128, 128, 512);
  transpose_k<<<dim3(16, 16), 256, 0, stream>>>(fc2_w, ws + FC2T, 512, 512, 512, 512);
  transpose_k<<<dim3(16, 48), 256, 0, stream>>>(w_ih0 + 64, ws + WIS, 1536, 512, 576, 1536);
  hgather_k<<<64, 128, 0, stream>>>(time_w, visit_w, tcont_w, irr0_w, irr1_w, cat0_w, cat1_w, ws + WTH);

  // static path: static_h, acc0
  gemm_k<<<8 * 16, 128, 0, stream>>>(z_static, ws + FC1T, fc1_b, ws + HID, 256, 128, 512, 1);
  gemm_k<<<8 * 16, 128, 0, stream>>>(ws + HID, ws + FC2T, fc2_b, ws + SHH, 256, 512, 512, 0);
  gemm_k<<<8 * 48, 128, 0, stream>>>(ws + SHH, ws + WIS, b_ih0, ws + ACC0, 256, 512, 1536, 0);

  // arrange MFMA weight fragments (3-way bf16 split)
  arrangeB1_k<<<(32 * 32 * 3 * 64 + 255) / 256, 256, 0, stream>>>(w_ih1, w_hh1, (ushort_t*)(ws + WB1));
  arrangeA0_k<<<(18 * 32 * 3 * 64 + 255) / 256, 256, 0, stream>>>(w_hh0, w_ih0, (ushort_t*)(ws + WA0));
  arrangeH_k<<<(16 * 4 * 64 + 255) / 256, 256, 0, stream>>>(ws + WTH, (ushort_t*)(ws + WH));

  // RNG keys: key(42) = (0,42); 6 children (partitionable fold-in)
  unsigned kk[6][2];
  for (int i = 0; i < 6; ++i) tf2x32(0u, 42u, 0u, (unsigned)i, &kk[i][0], &kk[i][1]);

  static_heads_k<<<256, 64, 0, stream>>>(ws + SHH, scont_w, scont_b, scat_w, scat_b, out,
                                         kk[5][0], kk[5][1]);

  // zero initial hidden states: f32 ping-pong parity 1 and bf16 splits parity 1
  hipMemsetAsync((void*)(ws + H0F + 131072), 0, 131072 * sizeof(float), stream);
  hipMemsetAsync((void*)(ws + H1F + 131072), 0, 131072 * sizeof(float), stream);
  hipMemsetAsync((void*)((ushort_t*)(ws + H0S) + 393216), 0, 393216 * sizeof(ushort_t), stream);
  hipMemsetAsync((void*)((ushort_t*)(ws + H1S) + 393216), 0, 393216 * sizeof(ushort_t), stream);

  HeadPtrs hp{time_b, visit_b, tcont_b, irr0_b, irr1_b, cat0_b, cat1_b};
  for (int s = 0; s <= 257; ++s)
    step_k<<<520, 256, 0, stream>>>(s, z_temporal, b_hh0, b_ih1, b_hh1, ws, hp);

  Keys ky{kk[0][0], kk[0][1], kk[1][0], kk[1][1], kk[2][0], kk[2][1],
          kk[3][0], kk[3][1], kk[4][0], kk[4][1]};
  final_k<<<256, 256, 0, stream>>>(ws, out, ky);
}